// Round 1
// baseline (382.207 us; speedup 1.0000x reference)
//
#include <hip/hip_runtime.h>
#include <math.h>

#define T_TGT 50
#define NCLS 80

__constant__ float c_anchors[18] = {10,13,16,30,33,23,30,61,62,45,
                                    59,119,116,90,156,198,373,326};

__device__ __forceinline__ float softplusf(float x){
    // log(1+exp(x)), stable
    return fmaxf(x, 0.f) + log1pf(expf(-fabsf(x)));
}
__device__ __forceinline__ float bcef(float x, float t){
    // -(t*log(sig(x)) + (1-t)*log(1-sig(x)))
    return t * softplusf(-x) + (1.f - t) * softplusf(x);
}

template<int H, int STRIDE, int GROUP>
__global__ __launch_bounds__(256)
void yolo_layer_kernel(const float* __restrict__ raw,
                       const float* __restrict__ targets,
                       float* __restrict__ out)
{
    constexpr int HH = H * H;
    constexpr int CELLS = 3 * HH;
    const int b = blockIdx.y;
    const int tid = threadIdx.x;

    // per-target metadata (recomputed per block; 50 targets, trivial cost)
    __shared__ float s_btlx[T_TGT], s_btly[T_TGT], s_bbrx[T_TGT], s_bbry[T_TGT];
    __shared__ float s_careab[T_TGT];             // 0.7 * truth area
    __shared__ int   s_key[T_TGT], s_cls[T_TGT];  // match key, class id
    __shared__ float s_fx[T_TGT], s_fy[T_TGT];    // xy targets (fractional)
    __shared__ float s_lw[T_TGT], s_lh[T_TGT];    // wh targets (log space)
    __shared__ float s_w2[T_TGT];                 // scale^2 = 2 - area/fs^2

    if (tid < T_TGT) {
        const float* lab = targets + ((size_t)b * T_TGT + tid) * 5;
        float cf = lab[0], x = lab[1], y = lab[2], w = lab[3], h = lab[4];
        bool valid = (cf + x + y + w + h) > 0.f;
        const float fs = (float)H;
        float tx = x * fs, ty = y * fs, tw = w * fs, th = h * fs;
        int gi = (int)tx, gj = (int)ty;
        float tarea = tw * th;
        // best anchor over all 9 (first-max wins, matching jnp.argmax)
        float best = -1.f; int bestn = 0;
        #pragma unroll
        for (int n = 0; n < 9; n++) {
            float aw = c_anchors[2*n]   * (1.f / STRIDE);
            float ah = c_anchors[2*n+1] * (1.f / STRIDE);
            float mw = fminf(tw, aw), mh = fminf(th, ah);
            float inter = (mw > 0.f && mh > 0.f) ? mw * mh : 0.f;
            float iou = inter / (tarea + aw * ah - inter);
            if (iou > best) { best = iou; bestn = n; }
        }
        bool sel = valid && ((bestn / 3) == GROUP);
        int bn = bestn % 3;
        s_key[tid]  = sel ? ((bn << 20) | (gj << 10) | gi) : -1;
        s_btlx[tid] = tx - tw * 0.5f;
        s_btly[tid] = ty - th * 0.5f;
        s_bbrx[tid] = tx + tw * 0.5f;
        s_bbry[tid] = ty + th * 0.5f;
        s_careab[tid] = 0.7f * tarea;
        s_w2[tid] = 2.f - tarea / (fs * fs);
        float awm = c_anchors[2*(3*GROUP + bn)]   * (1.f / STRIDE);
        float ahm = c_anchors[2*(3*GROUP + bn)+1] * (1.f / STRIDE);
        s_lw[tid] = logf(tw / awm + 1e-16f);
        s_lh[tid] = logf(th / ahm + 1e-16f);
        s_fx[tid] = tx - (float)gi;
        s_fy[tid] = ty - (float)gj;
        s_cls[tid] = (int)cf;
    }
    __syncthreads();

    float local = 0.f;
    const int c = blockIdx.x * 256 + tid;
    if (c < CELLS) {
        const int a   = c / HH;
        const int rem = c - a * HH;
        const int j   = rem / H;
        const int i   = rem - j * H;
        const float* base = raw + ((size_t)b * 255 + a * 85) * HH + rem;
        float x0 = base[0];
        float x1 = base[HH];
        float x2 = base[2 * HH];
        float x3 = base[3 * HH];
        float x4 = base[4 * HH];

        float s0 = 1.f / (1.f + expf(-x0));
        float s1 = 1.f / (1.f + expf(-x1));
        float manw = c_anchors[2*(3*GROUP + a)]   * (1.f / STRIDE);
        float manh = c_anchors[2*(3*GROUP + a)+1] * (1.f / STRIDE);
        float px = s0 + (float)i, py = s1 + (float)j;
        float pw = expf(x2) * manw, ph = expf(x3) * manh;
        float atlx = px - pw * 0.5f, atly = py - ph * 0.5f;
        float abrx = px + pw * 0.5f, abry = py + ph * 0.5f;
        float carea_a = 0.7f * (pw * ph);
        const int mykey = (a << 20) | (j << 10) | i;

        int winner = -1;
        bool ign = false;
        for (int t = 0; t < T_TGT; t++) {
            float tlx = fmaxf(atlx, s_btlx[t]);
            float tly = fmaxf(atly, s_btly[t]);
            float brx = fminf(abrx, s_bbrx[t]);
            float bry = fminf(abry, s_bbry[t]);
            float dx = brx - tlx, dy = bry - tly;
            float ai = dx * dy;
            // piou > 0.7  <=>  1.7*ai > 0.7*(area_a + area_b)   (when overlap>0)
            ign = ign || ((dx > 0.f) && (dy > 0.f) &&
                          (1.7f * ai > carea_a + s_careab[t]));
            if (s_key[t] == mykey) winner = t;  // last-write-wins like XLA scatter
        }

        if (winner >= 0) {
            // objectness target = 1 (obj_mask forced to 1 at matched cells)
            local += softplusf(-x4);
            float w2 = s_w2[winner];
            local += w2 * (bcef(x0, s_fx[winner]) + bcef(x1, s_fy[winner]));
            float dw = x2 - s_lw[winner];
            float dh = x3 - s_lh[winner];
            local += 0.5f * w2 * (dw * dw + dh * dh);
            int cls = s_cls[winner];
            for (int cc = 0; cc < NCLS; cc++) {
                float xc = base[(5 + cc) * HH];
                local += (cc == cls) ? softplusf(-xc) : softplusf(xc);
            }
        } else if (!ign) {
            local += softplusf(x4);  // objectness target = 0, not ignored
        }
    }

    // block reduction: wave64 shuffle -> LDS -> one atomic per block
    for (int off = 32; off > 0; off >>= 1)
        local += __shfl_down(local, off, 64);
    __shared__ float s_wsum[4];
    const int lane = tid & 63, wv = tid >> 6;
    if (lane == 0) s_wsum[wv] = local;
    __syncthreads();
    if (tid == 0)
        atomicAdd(out, s_wsum[0] + s_wsum[1] + s_wsum[2] + s_wsum[3]);
}

extern "C" void kernel_launch(void* const* d_in, const int* in_sizes, int n_in,
                              void* d_out, int out_size, void* d_ws, size_t ws_size,
                              hipStream_t stream)
{
    const float* out0 = (const float*)d_in[0];
    const float* out1 = (const float*)d_in[1];
    const float* out2 = (const float*)d_in[2];
    const float* tgt  = (const float*)d_in[3];
    float* out = (float*)d_out;

    const int B = in_sizes[3] / (T_TGT * 5);  // 16

    hipMemsetAsync(out, 0, sizeof(float), stream);

    {
        dim3 grid((3 * 19 * 19 + 255) / 256, B);
        yolo_layer_kernel<19, 32, 2><<<grid, 256, 0, stream>>>(out0, tgt, out);
    }
    {
        dim3 grid((3 * 38 * 38 + 255) / 256, B);
        yolo_layer_kernel<38, 16, 1><<<grid, 256, 0, stream>>>(out1, tgt, out);
    }
    {
        dim3 grid((3 * 76 * 76 + 255) / 256, B);
        yolo_layer_kernel<76, 8, 0><<<grid, 256, 0, stream>>>(out2, tgt, out);
    }
}

// Round 2
// 191.348 us; speedup vs baseline: 1.9974x; 1.9974x over previous
//
#include <hip/hip_runtime.h>
#include <math.h>

#define T_TGT 50
#define NCLS 80

__constant__ float c_anchors[18] = {10,13,16,30,33,23,30,61,62,45,
                                    59,119,116,90,156,198,373,326};

__device__ __forceinline__ float softplusf(float x){
    // log(1+exp(x)), stable
    return fmaxf(x, 0.f) + log1pf(expf(-fabsf(x)));
}
__device__ __forceinline__ float bcef(float x, float t){
    // -(t*log(sig(x)) + (1-t)*log(1-sig(x)))
    return t * softplusf(-x) + (1.f - t) * softplusf(x);
}

// ---------------------------------------------------------------------------
// Main per-cell kernel: channels 0-4 only (box + objectness). Class channels
// (5..84) are handled by yolo_class_kernel to avoid the serialized scattered-
// load tail that dominated round 1 (98 us tail wave, VALUBusy 2.4%).
// ---------------------------------------------------------------------------
template<int H, int STRIDE, int GROUP>
__global__ __launch_bounds__(256)
void yolo_layer_kernel(const float* __restrict__ raw,
                       const float* __restrict__ targets,
                       float* __restrict__ out)
{
    constexpr int HH = H * H;
    constexpr int CELLS = 3 * HH;
    const int b = blockIdx.y;
    const int tid = threadIdx.x;

    // per-target metadata, packed for 2-LDS-read hot loop
    __shared__ float4 s_box[T_TGT];    // tlx, tly, brx, bry
    __shared__ float2 s_misc[T_TGT];   // x = 0.7*truth_area, y = key (int bits)
    __shared__ float s_fx[T_TGT], s_fy[T_TGT];   // xy targets (fractional)
    __shared__ float s_lw[T_TGT], s_lh[T_TGT];   // wh targets (log space)
    __shared__ float s_w2[T_TGT];                // scale^2 = 2 - area/fs^2

    if (tid < T_TGT) {
        const float* lab = targets + ((size_t)b * T_TGT + tid) * 5;
        float cf = lab[0], x = lab[1], y = lab[2], w = lab[3], h = lab[4];
        bool valid = (cf + x + y + w + h) > 0.f;
        const float fs = (float)H;
        float tx = x * fs, ty = y * fs, tw = w * fs, th = h * fs;
        int gi = (int)tx, gj = (int)ty;
        float tarea = tw * th;
        // best anchor over all 9 (first-max wins, matching jnp.argmax)
        float best = -1.f; int bestn = 0;
        #pragma unroll
        for (int n = 0; n < 9; n++) {
            float aw = c_anchors[2*n]   * (1.f / STRIDE);
            float ah = c_anchors[2*n+1] * (1.f / STRIDE);
            float mw = fminf(tw, aw), mh = fminf(th, ah);
            float inter = (mw > 0.f && mh > 0.f) ? mw * mh : 0.f;
            float iou = inter / (tarea + aw * ah - inter);
            if (iou > best) { best = iou; bestn = n; }
        }
        bool sel = valid && ((bestn / 3) == GROUP);
        int bn = bestn % 3;
        int key = sel ? ((bn << 20) | (gj << 10) | gi) : -1;
        s_box[tid]  = make_float4(tx - tw*0.5f, ty - th*0.5f,
                                  tx + tw*0.5f, ty + th*0.5f);
        s_misc[tid] = make_float2(0.7f * tarea, __int_as_float(key));
        s_w2[tid] = 2.f - tarea / (fs * fs);
        float awm = c_anchors[2*(3*GROUP + bn)]   * (1.f / STRIDE);
        float ahm = c_anchors[2*(3*GROUP + bn)+1] * (1.f / STRIDE);
        s_lw[tid] = logf(tw / awm + 1e-16f);
        s_lh[tid] = logf(th / ahm + 1e-16f);
        s_fx[tid] = tx - (float)gi;
        s_fy[tid] = ty - (float)gj;
    }
    __syncthreads();

    float local = 0.f;
    const int c = blockIdx.x * 256 + tid;
    if (c < CELLS) {
        const int a   = c / HH;
        const int rem = c - a * HH;
        const int j   = rem / H;
        const int i   = rem - j * H;
        const float* base = raw + ((size_t)b * 255 + a * 85) * HH + rem;
        float x0 = base[0];
        float x1 = base[HH];
        float x2 = base[2 * HH];
        float x3 = base[3 * HH];
        float x4 = base[4 * HH];

        float s0 = 1.f / (1.f + expf(-x0));
        float s1 = 1.f / (1.f + expf(-x1));
        float manw = c_anchors[2*(3*GROUP + a)]   * (1.f / STRIDE);
        float manh = c_anchors[2*(3*GROUP + a)+1] * (1.f / STRIDE);
        float px = s0 + (float)i, py = s1 + (float)j;
        float pw = expf(x2) * manw, ph = expf(x3) * manh;
        float atlx = px - pw * 0.5f, atly = py - ph * 0.5f;
        float abrx = px + pw * 0.5f, abry = py + ph * 0.5f;
        float carea_a = 0.7f * (pw * ph);
        const int mykey = (a << 20) | (j << 10) | i;

        int winner = -1;
        bool ign = false;
        #pragma unroll 10
        for (int t = 0; t < T_TGT; t++) {
            float4 bx = s_box[t];
            float2 mi = s_misc[t];
            float tlx = fmaxf(atlx, bx.x);
            float tly = fmaxf(atly, bx.y);
            float brx = fminf(abrx, bx.z);
            float bry = fminf(abry, bx.w);
            float dx = brx - tlx, dy = bry - tly;
            // piou > 0.7  <=>  1.7*ai > 0.7*(area_a + area_b)  (when overlap>0)
            ign = ign || ((dx > 0.f) & (dy > 0.f) &
                          (1.7f * (dx * dy) > carea_a + mi.x));
            if (__float_as_int(mi.y) == mykey) winner = t;  // last-write-wins
        }

        if (winner >= 0) {
            local += softplusf(-x4);               // objectness target = 1
            float w2 = s_w2[winner];
            local += w2 * (bcef(x0, s_fx[winner]) + bcef(x1, s_fy[winner]));
            float dw = x2 - s_lw[winner];
            float dh = x3 - s_lh[winner];
            local += 0.5f * w2 * (dw * dw + dh * dh);
        } else if (!ign) {
            local += softplusf(x4);                // objectness target = 0
        }
    }

    // block reduction: wave64 shuffle -> LDS -> one atomic per block
    for (int off = 32; off > 0; off >>= 1)
        local += __shfl_down(local, off, 64);
    __shared__ float s_wsum[4];
    const int lane = tid & 63, wv = tid >> 6;
    if (lane == 0) s_wsum[wv] = local;
    __syncthreads();
    if (tid == 0)
        atomicAdd(out, s_wsum[0] + s_wsum[1] + s_wsum[2] + s_wsum[3]);
}

// ---------------------------------------------------------------------------
// Class-loss kernel: one wave per (target, batch, layer). Gathers all 80
// class logits of the matched cell in 2 vector-load instructions (one round
// trip) instead of 80 serialized per-lane loads.
// Class loss at a matched cell = sum_c softplus(x_c) - x_cls
//   (since softplus(-x) - softplus(x) == -x exactly).
// ---------------------------------------------------------------------------
__global__ __launch_bounds__(64)
void yolo_class_kernel(const float* __restrict__ r0,
                       const float* __restrict__ r1,
                       const float* __restrict__ r2,
                       const float* __restrict__ targets,
                       float* __restrict__ out)
{
    const int t0 = blockIdx.x;   // target index (0..49)
    const int b  = blockIdx.y;
    const int L  = blockIdx.z;   // layer (0..2)
    const int lane = threadIdx.x;

    const int Hs[3] = {19, 38, 76};
    const float inv_s[3] = {1.f/32.f, 1.f/16.f, 1.f/8.f};
    const int Gs[3] = {2, 1, 0};
    const float* raw = (L == 0) ? r0 : (L == 1) ? r1 : r2;
    const int H = Hs[L];
    const int HH = H * H;
    const float is = inv_s[L];
    const int group = Gs[L];

    int selkey = 0x40000000 | lane;   // unique sentinel, never matches a key
    int clsid = 0;
    if (lane < T_TGT) {
        const float* lab = targets + ((size_t)b * T_TGT + lane) * 5;
        float cf = lab[0], x = lab[1], y = lab[2], w = lab[3], h = lab[4];
        bool valid = (cf + x + y + w + h) > 0.f;
        float fs = (float)H;
        float tx = x * fs, ty = y * fs, tw = w * fs, th = h * fs;
        float tarea = tw * th;
        float best = -1.f; int bestn = 0;
        #pragma unroll
        for (int n = 0; n < 9; n++) {
            float aw = c_anchors[2*n] * is, ah = c_anchors[2*n+1] * is;
            float mw = fminf(tw, aw), mh = fminf(th, ah);
            float inter = (mw > 0.f && mh > 0.f) ? mw * mh : 0.f;
            float iou = inter / (tarea + aw * ah - inter);
            if (iou > best) { best = iou; bestn = n; }
        }
        if (valid && (bestn / 3) == group) {
            int bn = bestn % 3, gi = (int)tx, gj = (int)ty;
            selkey = (bn << 20) | (gj << 10) | gi;
        }
        clsid = (int)cf;
    }

    const int k0 = __shfl(selkey, t0);
    if (k0 & 0x40000000) return;              // target t0 not selected
    unsigned long long dup = __ballot(selkey == k0);
    if (dup >> (t0 + 1)) return;              // later target claims same cell
    const int cls0 = __shfl(clsid, t0);

    const int gi = k0 & 1023, gj = (k0 >> 10) & 1023, bn = k0 >> 20;
    const float* base = raw + ((size_t)b * 255 + bn * 85) * HH + gj * H + gi;

    float local;
    {
        float xc = base[(size_t)(5 + lane) * HH];          // classes 0..63
        local = softplusf(xc) - ((lane == cls0) ? xc : 0.f);
    }
    if (lane < 16) {
        float xc = base[(size_t)(69 + lane) * HH];         // classes 64..79
        local += softplusf(xc) - ((lane + 64 == cls0) ? xc : 0.f);
    }
    for (int off = 32; off > 0; off >>= 1)
        local += __shfl_down(local, off, 64);
    if (lane == 0)
        atomicAdd(out, local);
}

extern "C" void kernel_launch(void* const* d_in, const int* in_sizes, int n_in,
                              void* d_out, int out_size, void* d_ws, size_t ws_size,
                              hipStream_t stream)
{
    const float* out0 = (const float*)d_in[0];
    const float* out1 = (const float*)d_in[1];
    const float* out2 = (const float*)d_in[2];
    const float* tgt  = (const float*)d_in[3];
    float* out = (float*)d_out;

    const int B = in_sizes[3] / (T_TGT * 5);  // 16

    hipMemsetAsync(out, 0, sizeof(float), stream);

    {
        dim3 grid((3 * 19 * 19 + 255) / 256, B);
        yolo_layer_kernel<19, 32, 2><<<grid, 256, 0, stream>>>(out0, tgt, out);
    }
    {
        dim3 grid((3 * 38 * 38 + 255) / 256, B);
        yolo_layer_kernel<38, 16, 1><<<grid, 256, 0, stream>>>(out1, tgt, out);
    }
    {
        dim3 grid((3 * 76 * 76 + 255) / 256, B);
        yolo_layer_kernel<76, 8, 0><<<grid, 256, 0, stream>>>(out2, tgt, out);
    }
    {
        dim3 grid(T_TGT, B, 3);
        yolo_class_kernel<<<grid, 64, 0, stream>>>(out0, out1, out2, tgt, out);
    }
}

// Round 3
// 155.113 us; speedup vs baseline: 2.4641x; 1.2336x over previous
//
#include <hip/hip_runtime.h>
#include <math.h>

#define T_TGT 50
#define NCLS 80
#define NBATCH 16

// blocks per batch per layer: ceil(3*H*H / 256)
#define NB_L0 5     // 3*19*19 = 1083
#define NB_L1 17    // 3*38*38 = 4332
#define NB_L2 68    // 3*76*76 = 17328
#define NB_MAIN ((NB_L0 + NB_L1 + NB_L2) * NBATCH)   // 1440
#define N_CLS_UNITS (T_TGT * NBATCH * 3)             // 2400
#define NB_CLS ((N_CLS_UNITS + 3) / 4)               // 600 (4 waves/block)
#define NB_TOTAL (NB_MAIN + NB_CLS)                  // 2040

__constant__ float c_anchors[18] = {10,13,16,30,33,23,30,61,62,45,
                                    59,119,116,90,156,198,373,326};

__device__ __forceinline__ float softplusf(float x){
    return fmaxf(x, 0.f) + log1pf(expf(-fabsf(x)));
}
__device__ __forceinline__ float bcef(float x, float t){
    return t * softplusf(-x) + (1.f - t) * softplusf(x);
}

struct TgtMeta {
    float4 box;      // tlx, tly, brx, bry
    float2 misc;     // x = 0.7*truth_area, y = key (int bits)
    float fx, fy;    // xy targets (fractional)
    float lw, lh;    // wh targets (log space)
    float w2;        // scale^2 = 2 - area/fs^2
};

// per-cell work for one layer; returns this thread's loss contribution
template<int H, int STRIDE, int GROUP>
__device__ float main_cells(const float* __restrict__ raw,
                            const float* __restrict__ targets,
                            int b, int cb, int tid, TgtMeta* s_t)
{
    constexpr int HH = H * H;
    constexpr int CELLS = 3 * HH;

    if (tid < T_TGT) {
        const float* lab = targets + ((size_t)b * T_TGT + tid) * 5;
        float cf = lab[0], x = lab[1], y = lab[2], w = lab[3], h = lab[4];
        bool valid = (cf + x + y + w + h) > 0.f;
        const float fs = (float)H;
        float tx = x * fs, ty = y * fs, tw = w * fs, th = h * fs;
        int gi = (int)tx, gj = (int)ty;
        float tarea = tw * th;
        float best = -1.f; int bestn = 0;
        #pragma unroll
        for (int n = 0; n < 9; n++) {
            float aw = c_anchors[2*n]   * (1.f / STRIDE);
            float ah = c_anchors[2*n+1] * (1.f / STRIDE);
            float mw = fminf(tw, aw), mh = fminf(th, ah);
            float inter = (mw > 0.f && mh > 0.f) ? mw * mh : 0.f;
            float iou = inter / (tarea + aw * ah - inter);
            if (iou > best) { best = iou; bestn = n; }
        }
        bool sel = valid && ((bestn / 3) == GROUP);
        int bn = bestn % 3;
        int key = sel ? ((bn << 20) | (gj << 10) | gi) : -1;
        s_t[tid].box  = make_float4(tx - tw*0.5f, ty - th*0.5f,
                                    tx + tw*0.5f, ty + th*0.5f);
        s_t[tid].misc = make_float2(0.7f * tarea, __int_as_float(key));
        s_t[tid].w2 = 2.f - tarea / (fs * fs);
        float awm = c_anchors[2*(3*GROUP + bn)]   * (1.f / STRIDE);
        float ahm = c_anchors[2*(3*GROUP + bn)+1] * (1.f / STRIDE);
        s_t[tid].lw = logf(tw / awm + 1e-16f);
        s_t[tid].lh = logf(th / ahm + 1e-16f);
        s_t[tid].fx = tx - (float)gi;
        s_t[tid].fy = ty - (float)gj;
    }
    __syncthreads();

    float local = 0.f;
    const int c = cb * 256 + tid;
    if (c < CELLS) {
        const int a   = c / HH;
        const int rem = c - a * HH;
        const int j   = rem / H;
        const int i   = rem - j * H;
        const float* base = raw + ((size_t)b * 255 + a * 85) * HH + rem;
        float x0 = base[0];
        float x1 = base[HH];
        float x2 = base[2 * HH];
        float x3 = base[3 * HH];
        float x4 = base[4 * HH];

        float s0 = 1.f / (1.f + expf(-x0));
        float s1 = 1.f / (1.f + expf(-x1));
        float manw = c_anchors[2*(3*GROUP + a)]   * (1.f / STRIDE);
        float manh = c_anchors[2*(3*GROUP + a)+1] * (1.f / STRIDE);
        float px = s0 + (float)i, py = s1 + (float)j;
        float pw = expf(x2) * manw, ph = expf(x3) * manh;
        float atlx = px - pw * 0.5f, atly = py - ph * 0.5f;
        float abrx = px + pw * 0.5f, abry = py + ph * 0.5f;
        float carea_a = 0.7f * (pw * ph);
        const int mykey = (a << 20) | (j << 10) | i;

        int winner = -1;
        bool ign = false;
        #pragma unroll 10
        for (int t = 0; t < T_TGT; t++) {
            float4 bx = s_t[t].box;
            float2 mi = s_t[t].misc;
            float tlx = fmaxf(atlx, bx.x);
            float tly = fmaxf(atly, bx.y);
            float brx = fminf(abrx, bx.z);
            float bry = fminf(abry, bx.w);
            float dx = brx - tlx, dy = bry - tly;
            // piou > 0.7  <=>  1.7*ai > 0.7*(area_a + area_b)  (overlap > 0)
            ign = ign || ((dx > 0.f) & (dy > 0.f) &
                          (1.7f * (dx * dy) > carea_a + mi.x));
            if (__float_as_int(mi.y) == mykey) winner = t;  // last-write-wins
        }

        if (winner >= 0) {
            local += softplusf(-x4);               // objectness target = 1
            float w2 = s_t[winner].w2;
            local += w2 * (bcef(x0, s_t[winner].fx) + bcef(x1, s_t[winner].fy));
            float dw = x2 - s_t[winner].lw;
            float dh = x3 - s_t[winner].lh;
            local += 0.5f * w2 * (dw * dw + dh * dh);
        } else if (!ign) {
            local += softplusf(x4);                // objectness target = 0
        }
    }
    return local;
}

// class loss for one (target, batch, layer) unit, handled by one wave
__device__ float class_unit(const float* __restrict__ r0,
                            const float* __restrict__ r1,
                            const float* __restrict__ r2,
                            const float* __restrict__ targets,
                            int u, int lane)
{
    const int L   = u / (T_TGT * NBATCH);
    const int rem = u - L * (T_TGT * NBATCH);
    const int b   = rem / T_TGT;
    const int t0  = rem - b * T_TGT;

    const int Hs[3] = {19, 38, 76};
    const float inv_s[3] = {1.f/32.f, 1.f/16.f, 1.f/8.f};
    const int Gs[3] = {2, 1, 0};
    const float* raw = (L == 0) ? r0 : (L == 1) ? r1 : r2;
    const int H = Hs[L];
    const int HH = H * H;
    const float is = inv_s[L];
    const int group = Gs[L];

    int selkey = 0x40000000 | lane;   // sentinel, never matches a real key
    int clsid = 0;
    if (lane < T_TGT) {
        const float* lab = targets + ((size_t)b * T_TGT + lane) * 5;
        float cf = lab[0], x = lab[1], y = lab[2], w = lab[3], h = lab[4];
        bool valid = (cf + x + y + w + h) > 0.f;
        float fs = (float)H;
        float tx = x * fs, ty = y * fs, tw = w * fs, th = h * fs;
        float tarea = tw * th;
        float best = -1.f; int bestn = 0;
        #pragma unroll
        for (int n = 0; n < 9; n++) {
            float aw = c_anchors[2*n] * is, ah = c_anchors[2*n+1] * is;
            float mw = fminf(tw, aw), mh = fminf(th, ah);
            float inter = (mw > 0.f && mh > 0.f) ? mw * mh : 0.f;
            float iou = inter / (tarea + aw * ah - inter);
            if (iou > best) { best = iou; bestn = n; }
        }
        if (valid && (bestn / 3) == group) {
            int bn = bestn % 3, gi = (int)tx, gj = (int)ty;
            selkey = (bn << 20) | (gj << 10) | gi;
        }
        clsid = (int)cf;
    }

    const int k0 = __shfl(selkey, t0);
    bool active = !(k0 & 0x40000000);                 // t0 selected?
    unsigned long long dup = __ballot(selkey == k0);
    active = active && !(dup >> (t0 + 1));            // later target wins cell

    float local = 0.f;
    if (active) {   // wave-uniform branch
        const int cls0 = __shfl(clsid, t0);
        const int gi = k0 & 1023, gj = (k0 >> 10) & 1023, bn = k0 >> 20;
        const float* base = raw + ((size_t)b * 255 + bn * 85) * HH + gj * H + gi;
        // class loss = sum_c softplus(x_c) - x_cls
        float xc = base[(size_t)(5 + lane) * HH];               // classes 0..63
        local = softplusf(xc) - ((lane == cls0) ? xc : 0.f);
        if (lane < 16) {
            float xh = base[(size_t)(69 + lane) * HH];          // classes 64..79
            local += softplusf(xh) - ((lane + 64 == cls0) ? xh : 0.f);
        }
    }
    return local;
}

__global__ __launch_bounds__(256)
void yolo_fused(const float* __restrict__ r0,
                const float* __restrict__ r1,
                const float* __restrict__ r2,
                const float* __restrict__ targets,
                float* __restrict__ partial)
{
    __shared__ TgtMeta s_t[T_TGT];
    __shared__ float s_wsum[4];

    const int blk = blockIdx.x;
    const int tid = threadIdx.x;
    float local = 0.f;

    if (blk < NB_L0 * NBATCH) {
        int b = blk / NB_L0, cb = blk - b * NB_L0;
        local = main_cells<19, 32, 2>(r0, targets, b, cb, tid, s_t);
    } else if (blk < (NB_L0 + NB_L1) * NBATCH) {
        int q = blk - NB_L0 * NBATCH;
        int b = q / NB_L1, cb = q - b * NB_L1;
        local = main_cells<38, 16, 1>(r1, targets, b, cb, tid, s_t);
    } else if (blk < NB_MAIN) {
        int q = blk - (NB_L0 + NB_L1) * NBATCH;
        int b = q / NB_L2, cb = q - b * NB_L2;
        local = main_cells<76, 8, 0>(r2, targets, b, cb, tid, s_t);
    } else {
        int u = (blk - NB_MAIN) * 4 + (tid >> 6);
        if (u < N_CLS_UNITS)
            local = class_unit(r0, r1, r2, targets, u, tid & 63);
    }

    // block reduction -> unique partial slot (no global atomics)
    for (int off = 32; off > 0; off >>= 1)
        local += __shfl_down(local, off, 64);
    const int lane = tid & 63, wv = tid >> 6;
    if (lane == 0) s_wsum[wv] = local;
    __syncthreads();
    if (tid == 0)
        partial[blk] = s_wsum[0] + s_wsum[1] + s_wsum[2] + s_wsum[3];
}

__global__ __launch_bounds__(256)
void yolo_reduce(const float* __restrict__ partial, float* __restrict__ out)
{
    const int tid = threadIdx.x;
    float s = 0.f;
    for (int i = tid; i < NB_TOTAL; i += 256) s += partial[i];
    for (int off = 32; off > 0; off >>= 1)
        s += __shfl_down(s, off, 64);
    __shared__ float w[4];
    if ((tid & 63) == 0) w[tid >> 6] = s;
    __syncthreads();
    if (tid == 0) out[0] = w[0] + w[1] + w[2] + w[3];
}

extern "C" void kernel_launch(void* const* d_in, const int* in_sizes, int n_in,
                              void* d_out, int out_size, void* d_ws, size_t ws_size,
                              hipStream_t stream)
{
    const float* out0 = (const float*)d_in[0];
    const float* out1 = (const float*)d_in[1];
    const float* out2 = (const float*)d_in[2];
    const float* tgt  = (const float*)d_in[3];
    float* out = (float*)d_out;
    float* partial = (float*)d_ws;   // NB_TOTAL floats, all slots written

    yolo_fused<<<NB_TOTAL, 256, 0, stream>>>(out0, out1, out2, tgt, partial);
    yolo_reduce<<<1, 256, 0, stream>>>(partial, out);
}